// Round 3
// baseline (7597.375 us; speedup 1.0000x reference)
//
#include <hip/hip_runtime.h>
#include <stdint.h>

// Problem constants
#define B_   4
#define S_   4096
#define D_   1280
#define H_   20
#define HD_  64
#define SKV_ 77
#define CD_  2048

typedef short bfrag8 __attribute__((ext_vector_type(8)));   // 8 bf16 = 4 VGPRs
typedef float f32x4  __attribute__((ext_vector_type(4)));

__device__ __forceinline__ float bf2f(unsigned short h) {
  return __uint_as_float(((unsigned int)h) << 16);
}
__device__ __forceinline__ unsigned short f2bf(float f) {
  unsigned int u = __float_as_uint(f);
  unsigned int r = (u + 0x7FFFu + ((u >> 16) & 1u)) >> 16;  // RNE
  return (unsigned short)r;
}
__device__ __forceinline__ float cvtlo(unsigned int u) { return __uint_as_float(u << 16); }
__device__ __forceinline__ float cvthi(unsigned int u) { return __uint_as_float(u & 0xFFFF0000u); }

// ---------------------------------------------------------------------------
// fp32 -> bf16 conversion (vectorized: float4 in, 4 packed bf16 out)
// ---------------------------------------------------------------------------
__global__ __launch_bounds__(256) void convert_k(const float* __restrict__ src,
                                                 unsigned short* __restrict__ dst,
                                                 int n4) {
  for (int i = blockIdx.x * 256 + threadIdx.x; i < n4; i += gridDim.x * 256) {
    float4 v = ((const float4*)src)[i];
    uint2 o;
    o.x = (unsigned int)f2bf(v.x) | ((unsigned int)f2bf(v.y) << 16);
    o.y = (unsigned int)f2bf(v.z) | ((unsigned int)f2bf(v.w) << 16);
    ((uint2*)dst)[i] = o;
  }
}

// ---------------------------------------------------------------------------
// boost scalar: ratio = mean(mask); 64x64 bilinear resize to 64x64 = identity
// ---------------------------------------------------------------------------
__global__ __launch_bounds__(256) void boost_k(const float* __restrict__ mask,
                                               float* __restrict__ outp) {
  __shared__ float red[4];
  float s = 0.f;
  for (int i = threadIdx.x; i < S_; i += 256) s += mask[i];
#pragma unroll
  for (int off = 32; off > 0; off >>= 1) s += __shfl_down(s, off, 64);
  int wave = threadIdx.x >> 6, lane = threadIdx.x & 63;
  if (lane == 0) red[wave] = s;
  __syncthreads();
  if (threadIdx.x == 0) {
    float t = red[0] + red[1] + red[2] + red[3];
    float ratio = t * (1.0f / (float)S_);
    float boost = (ratio > 1e-6f && ratio < 0.1f)
                      ? fminf(1.0f + (0.1f - ratio) * 30.0f, 4.0f)
                      : 1.0f;
    outp[0] = boost;
  }
}

// ---------------------------------------------------------------------------
// C[M,N] = A[M,K] @ B[K,N] (+bias), bf16 in, fp32 accum, MFMA 16x16x32.
// Block 256 thr = 4 waves; tile 64(M) x 64(N), K-step 32.
// f32out selects the store dtype (fp32 for the final projection).
// ---------------------------------------------------------------------------
__global__ __launch_bounds__(256) void gemm_bf16(
    const unsigned short* __restrict__ A, const unsigned short* __restrict__ Bw,
    void* __restrict__ C, int M, int N, int K,
    const float* __restrict__ bias, int f32out) {
  __shared__ unsigned short As[64][40];  // [m][k], pad 8 keeps b128 reads clean
  __shared__ unsigned short Bs[64][40];  // [n][k] (transposed tile)

  const int tid = threadIdx.x;
  const int m0 = blockIdx.x * 64, n0 = blockIdx.y * 64;
  const int wave = tid >> 6, lane = tid & 63;
  const int l16 = lane & 15, quad = lane >> 4;

  f32x4 acc[4] = {};

  for (int k0 = 0; k0 < K; k0 += 32) {
    {
      int row = tid >> 2, kc = tid & 3;
      int gr = m0 + row;
      uint4 v = make_uint4(0u, 0u, 0u, 0u);
      if (gr < M) v = *(const uint4*)(A + (size_t)gr * K + k0 + kc * 8);
      *(uint4*)&As[row][kc * 8] = v;
    }
    {
      int kk = tid >> 3, n8 = tid & 7;
      uint4 v = *(const uint4*)(Bw + (size_t)(k0 + kk) * N + n0 + n8 * 8);
      unsigned short* p = (unsigned short*)&v;
#pragma unroll
      for (int j = 0; j < 8; ++j) Bs[n8 * 8 + j][kk] = p[j];
    }
    __syncthreads();

    // A-frag: row m = lane&15, k = quad*8+j ; B-frag: col n = lane&15, same k
    bfrag8 af = *(const bfrag8*)&As[wave * 16 + l16][quad * 8];
#pragma unroll
    for (int nt = 0; nt < 4; ++nt) {
      bfrag8 bf = *(const bfrag8*)&Bs[nt * 16 + l16][quad * 8];
      acc[nt] = __builtin_amdgcn_mfma_f32_16x16x32_bf16(af, bf, acc[nt], 0, 0, 0);
    }
    __syncthreads();
  }

  // D layout: row = quad*4 + r, col = lane&15  (m89/m91-verified)
#pragma unroll
  for (int nt = 0; nt < 4; ++nt) {
#pragma unroll
    for (int r = 0; r < 4; ++r) {
      int row = m0 + wave * 16 + quad * 4 + r;
      if (row < M) {
        int col = n0 + nt * 16 + l16;
        float v = acc[nt][r];
        if (bias) v += bias[col];
        if (f32out) ((float*)C)[(size_t)row * N + col] = v;
        else ((unsigned short*)C)[(size_t)row * N + col] = f2bf(v);
      }
    }
  }
}

// ---------------------------------------------------------------------------
// Attention: one thread per (b,h,q-row), online softmax, K/V head slice in LDS.
// hs[b,s,h*64+d] = base + mask[s]*boost*ip     (hs stored bf16)
// ---------------------------------------------------------------------------
__global__ __launch_bounds__(128) void attn_k(
    const unsigned short* __restrict__ Q, const unsigned short* __restrict__ Kb,
    const unsigned short* __restrict__ Vb, const unsigned short* __restrict__ Kip,
    const unsigned short* __restrict__ Vip, const float* __restrict__ mask,
    const float* __restrict__ boostp, unsigned short* __restrict__ hs) {
  __shared__ unsigned short Ks[SKV_ * HD_];
  __shared__ unsigned short Vs[SKV_ * HD_];
  __shared__ unsigned short obase[128 * 66];

  const int tid = threadIdx.x;
  const int bh = blockIdx.y;
  const int b = bh / H_, h = bh % H_;
  const int s = blockIdx.x * 128 + tid;

  auto stage = [&](const unsigned short* K1, const unsigned short* V1) {
    for (int idx = tid; idx < SKV_ * 16; idx += 128) {
      int row = idx >> 4, c4 = idx & 15;
      size_t goff = (size_t)(b * SKV_ + row) * D_ + h * HD_ + c4 * 4;
      *(uint2*)(Ks + row * HD_ + c4 * 4) = *(const uint2*)(K1 + goff);
      *(uint2*)(Vs + row * HD_ + c4 * 4) = *(const uint2*)(V1 + goff);
    }
  };

  float qf[64];
  {
    const uint4* qp = (const uint4*)(Q + (size_t)(b * S_ + s) * D_ + h * HD_);
#pragma unroll
    for (int i = 0; i < 8; ++i) {
      uint4 v = qp[i];
      qf[i * 8 + 0] = cvtlo(v.x); qf[i * 8 + 1] = cvthi(v.x);
      qf[i * 8 + 2] = cvtlo(v.y); qf[i * 8 + 3] = cvthi(v.y);
      qf[i * 8 + 4] = cvtlo(v.z); qf[i * 8 + 5] = cvthi(v.z);
      qf[i * 8 + 6] = cvtlo(v.w); qf[i * 8 + 7] = cvthi(v.w);
    }
  }

  float outv[64];
  auto branch = [&]() {
#pragma unroll
    for (int d = 0; d < 64; ++d) outv[d] = 0.f;
    float mrun = -1e30f, lrun = 0.f;
    for (int j = 0; j < SKV_; ++j) {
      float sum = 0.f;
      const uint4* kr = (const uint4*)(Ks + j * HD_);
#pragma unroll
      for (int i = 0; i < 8; ++i) {
        uint4 v = kr[i];
        sum = fmaf(qf[i * 8 + 0], cvtlo(v.x), sum); sum = fmaf(qf[i * 8 + 1], cvthi(v.x), sum);
        sum = fmaf(qf[i * 8 + 2], cvtlo(v.y), sum); sum = fmaf(qf[i * 8 + 3], cvthi(v.y), sum);
        sum = fmaf(qf[i * 8 + 4], cvtlo(v.z), sum); sum = fmaf(qf[i * 8 + 5], cvthi(v.z), sum);
        sum = fmaf(qf[i * 8 + 6], cvtlo(v.w), sum); sum = fmaf(qf[i * 8 + 7], cvthi(v.w), sum);
      }
      float sc = sum * 0.125f;  // 1/sqrt(64)
      float mn = fmaxf(mrun, sc);
      float alpha = __expf(mrun - mn);
      float p = __expf(sc - mn);
      lrun = lrun * alpha + p;
      if (alpha != 1.0f) {
#pragma unroll
        for (int d = 0; d < 64; ++d) outv[d] *= alpha;
      }
      const uint4* vr = (const uint4*)(Vs + j * HD_);
#pragma unroll
      for (int i = 0; i < 8; ++i) {
        uint4 v = vr[i];
        outv[i * 8 + 0] = fmaf(p, cvtlo(v.x), outv[i * 8 + 0]);
        outv[i * 8 + 1] = fmaf(p, cvthi(v.x), outv[i * 8 + 1]);
        outv[i * 8 + 2] = fmaf(p, cvtlo(v.y), outv[i * 8 + 2]);
        outv[i * 8 + 3] = fmaf(p, cvthi(v.y), outv[i * 8 + 3]);
        outv[i * 8 + 4] = fmaf(p, cvtlo(v.z), outv[i * 8 + 4]);
        outv[i * 8 + 5] = fmaf(p, cvthi(v.z), outv[i * 8 + 5]);
        outv[i * 8 + 6] = fmaf(p, cvtlo(v.w), outv[i * 8 + 6]);
        outv[i * 8 + 7] = fmaf(p, cvthi(v.w), outv[i * 8 + 7]);
      }
      mrun = mn;
    }
    float inv = 1.0f / lrun;
#pragma unroll
    for (int d = 0; d < 64; ++d) outv[d] *= inv;
  };

  stage(Kb, Vb);
  __syncthreads();
  branch();
#pragma unroll
  for (int d = 0; d < 64; ++d) obase[tid * 66 + d] = f2bf(outv[d]);
  __syncthreads();

  stage(Kip, Vip);
  __syncthreads();
  branch();

  const float scale = mask[s] * boostp[0];
  unsigned short* op = hs + (size_t)(b * S_ + s) * D_ + h * HD_;
#pragma unroll
  for (int i = 0; i < 8; ++i) {
    unsigned int w[4];
#pragma unroll
    for (int k2 = 0; k2 < 4; ++k2) {
      int d = i * 8 + k2 * 2;
      unsigned short lo = f2bf(bf2f(obase[tid * 66 + d]) + scale * outv[d]);
      unsigned short hi = f2bf(bf2f(obase[tid * 66 + d + 1]) + scale * outv[d + 1]);
      w[k2] = (unsigned int)lo | ((unsigned int)hi << 16);
    }
    uint4 v; v.x = w[0]; v.y = w[1]; v.z = w[2]; v.w = w[3];
    ((uint4*)op)[i] = v;
  }
}

// ---------------------------------------------------------------------------
extern "C" void kernel_launch(void* const* d_in, const int* in_sizes, int n_in,
                              void* d_out, int out_size, void* d_ws, size_t ws_size,
                              hipStream_t stream) {
  // Inputs are fp32 (per reference); output is fp32.
  const float* hidden = (const float*)d_in[0];
  const float* enc    = (const float*)d_in[1];
  const float* mask   = (const float*)d_in[2];
  const float* Wq     = (const float*)d_in[3];
  const float* Wk     = (const float*)d_in[4];
  const float* Wv     = (const float*)d_in[5];
  const float* Wkip   = (const float*)d_in[6];
  const float* Wvip   = (const float*)d_in[7];
  const float* Wo     = (const float*)d_in[8];
  const float* bo     = (const float*)d_in[9];

  char* ws = (char*)d_ws;
  // bf16 workspace copies. hsb aliases cHid (dead after Q-projection).
  unsigned short* cHid  = (unsigned short*)(ws + 0ULL);           // 41,943,040
  unsigned short* hsb   = cHid;                                   // alias
  unsigned short* cEnc  = (unsigned short*)(ws + 41943040ULL);    //  1,261,568
  unsigned short* cWq   = (unsigned short*)(ws + 43204608ULL);    //  3,276,800
  unsigned short* cWk   = (unsigned short*)(ws + 46481408ULL);    //  5,242,880
  unsigned short* cWv   = (unsigned short*)(ws + 51724288ULL);    //  5,242,880
  unsigned short* cWkip = (unsigned short*)(ws + 56967168ULL);    //  5,242,880
  unsigned short* cWvip = (unsigned short*)(ws + 62210048ULL);    //  5,242,880
  unsigned short* cWo   = (unsigned short*)(ws + 67452928ULL);    //  3,276,800
  unsigned short* Qb    = (unsigned short*)(ws + 70729728ULL);    // 41,943,040
  unsigned short* Kb    = (unsigned short*)(ws + 112672768ULL);   //    788,480
  unsigned short* Vb    = (unsigned short*)(ws + 113461248ULL);
  unsigned short* Kip   = (unsigned short*)(ws + 114249728ULL);
  unsigned short* Vip   = (unsigned short*)(ws + 115038208ULL);
  float* boostp         = (float*)(ws + 115826688ULL);
  // total ~115.83 MB

  struct CvtJob { const float* src; unsigned short* dst; int n; };
  const CvtJob jobs[8] = {
      {hidden, cHid, B_ * S_ * D_},  {enc, cEnc, B_ * SKV_ * CD_},
      {Wq, cWq, D_ * D_},            {Wk, cWk, CD_ * D_},
      {Wv, cWv, CD_ * D_},           {Wkip, cWkip, CD_ * D_},
      {Wvip, cWvip, CD_ * D_},       {Wo, cWo, D_ * D_}};
  for (int i = 0; i < 8; ++i) {
    int n4 = jobs[i].n >> 2;
    int g = (n4 + 255) / 256; if (g > 4096) g = 4096;
    convert_k<<<dim3(g), dim3(256), 0, stream>>>(jobs[i].src, jobs[i].dst, n4);
  }

  boost_k<<<dim3(1), dim3(256), 0, stream>>>(mask, boostp);

  const int MQ = B_ * S_;    // 16384
  const int MKV = B_ * SKV_; // 308

  // Q = hidden @ Wq  (bf16 out)
  gemm_bf16<<<dim3(256, 20), dim3(256), 0, stream>>>(cHid, cWq, Qb, MQ, D_, D_,
                                                     nullptr, 0);
  // K/V/Kip/Vip = enc @ W*  (bf16 out)
  gemm_bf16<<<dim3(5, 20), dim3(256), 0, stream>>>(cEnc, cWk, Kb, MKV, D_, CD_, nullptr, 0);
  gemm_bf16<<<dim3(5, 20), dim3(256), 0, stream>>>(cEnc, cWv, Vb, MKV, D_, CD_, nullptr, 0);
  gemm_bf16<<<dim3(5, 20), dim3(256), 0, stream>>>(cEnc, cWkip, Kip, MKV, D_, CD_, nullptr, 0);
  gemm_bf16<<<dim3(5, 20), dim3(256), 0, stream>>>(cEnc, cWvip, Vip, MKV, D_, CD_, nullptr, 0);

  // fused two-branch attention + mask/boost combine -> hsb (bf16, aliases cHid)
  attn_k<<<dim3(S_ / 128, B_ * H_), dim3(128), 0, stream>>>(Qb, Kb, Vb, Kip, Vip,
                                                            mask, boostp, hsb);

  // out = hsb @ Wo + bo   (fp32 output + fp32 bias)
  gemm_bf16<<<dim3(256, 20), dim3(256), 0, stream>>>(hsb, cWo, d_out, MQ, D_, D_,
                                                     bo, 1);
}

// Round 4
// 1316.637 us; speedup vs baseline: 5.7703x; 5.7703x over previous
//
#include <hip/hip_runtime.h>
#include <stdint.h>

// Problem constants
#define B_   4
#define S_   4096
#define D_   1280
#define H_   20
#define HD_  64
#define SKV_ 77
#define CD_  2048

typedef short bfrag8 __attribute__((ext_vector_type(8)));   // 8 bf16 = 4 VGPRs
typedef float f32x4  __attribute__((ext_vector_type(4)));

__device__ __forceinline__ float bf2f(unsigned short h) {
  return __uint_as_float(((unsigned int)h) << 16);
}
__device__ __forceinline__ unsigned short f2bf(float f) {
  unsigned int u = __float_as_uint(f);
  unsigned int r = (u + 0x7FFFu + ((u >> 16) & 1u)) >> 16;  // RNE
  return (unsigned short)r;
}
__device__ __forceinline__ float cvtlo(unsigned int u) { return __uint_as_float(u << 16); }
__device__ __forceinline__ float cvthi(unsigned int u) { return __uint_as_float(u & 0xFFFF0000u); }

// ---------------------------------------------------------------------------
// fp32 -> bf16 conversion (vectorized: float4 in, 4 packed bf16 out)
// ---------------------------------------------------------------------------
__global__ __launch_bounds__(256) void convert_k(const float* __restrict__ src,
                                                 unsigned short* __restrict__ dst,
                                                 int n4) {
  for (int i = blockIdx.x * 256 + threadIdx.x; i < n4; i += gridDim.x * 256) {
    float4 v = ((const float4*)src)[i];
    uint2 o;
    o.x = (unsigned int)f2bf(v.x) | ((unsigned int)f2bf(v.y) << 16);
    o.y = (unsigned int)f2bf(v.z) | ((unsigned int)f2bf(v.w) << 16);
    ((uint2*)dst)[i] = o;
  }
}

// ---------------------------------------------------------------------------
// boost scalar: ratio = mean(mask); 64x64 bilinear resize to 64x64 = identity
// ---------------------------------------------------------------------------
__global__ __launch_bounds__(256) void boost_k(const float* __restrict__ mask,
                                               float* __restrict__ outp) {
  __shared__ float red[4];
  float s = 0.f;
  for (int i = threadIdx.x; i < S_; i += 256) s += mask[i];
#pragma unroll
  for (int off = 32; off > 0; off >>= 1) s += __shfl_down(s, off, 64);
  int wave = threadIdx.x >> 6, lane = threadIdx.x & 63;
  if (lane == 0) red[wave] = s;
  __syncthreads();
  if (threadIdx.x == 0) {
    float t = red[0] + red[1] + red[2] + red[3];
    float ratio = t * (1.0f / (float)S_);
    float boost = (ratio > 1e-6f && ratio < 0.1f)
                      ? fminf(1.0f + (0.1f - ratio) * 30.0f, 4.0f)
                      : 1.0f;
    outp[0] = boost;
  }
}

// ---------------------------------------------------------------------------
// C[M,N] = A[M,K] @ B[K,N] (+bias), bf16 in, fp32 accum, MFMA 16x16x32.
// Block 256 thr = 4 waves; tile 64(M) x 64(N), K-step 32.
// ---------------------------------------------------------------------------
__global__ __launch_bounds__(256) void gemm_bf16(
    const unsigned short* __restrict__ A, const unsigned short* __restrict__ Bw,
    void* __restrict__ C, int M, int N, int K,
    const float* __restrict__ bias, int f32out) {
  __shared__ unsigned short As[64][40];
  __shared__ unsigned short Bs[64][40];

  const int tid = threadIdx.x;
  const int m0 = blockIdx.x * 64, n0 = blockIdx.y * 64;
  const int wave = tid >> 6, lane = tid & 63;
  const int l16 = lane & 15, quad = lane >> 4;

  f32x4 acc[4] = {};

  for (int k0 = 0; k0 < K; k0 += 32) {
    {
      int row = tid >> 2, kc = tid & 3;
      int gr = m0 + row;
      uint4 v = make_uint4(0u, 0u, 0u, 0u);
      if (gr < M) v = *(const uint4*)(A + (size_t)gr * K + k0 + kc * 8);
      *(uint4*)&As[row][kc * 8] = v;
    }
    {
      int kk = tid >> 3, n8 = tid & 7;
      uint4 v = *(const uint4*)(Bw + (size_t)(k0 + kk) * N + n0 + n8 * 8);
      unsigned short* p = (unsigned short*)&v;
#pragma unroll
      for (int j = 0; j < 8; ++j) Bs[n8 * 8 + j][kk] = p[j];
    }
    __syncthreads();

    bfrag8 af = *(const bfrag8*)&As[wave * 16 + l16][quad * 8];
#pragma unroll
    for (int nt = 0; nt < 4; ++nt) {
      bfrag8 bf = *(const bfrag8*)&Bs[nt * 16 + l16][quad * 8];
      acc[nt] = __builtin_amdgcn_mfma_f32_16x16x32_bf16(af, bf, acc[nt], 0, 0, 0);
    }
    __syncthreads();
  }

#pragma unroll
  for (int nt = 0; nt < 4; ++nt) {
#pragma unroll
    for (int r = 0; r < 4; ++r) {
      int row = m0 + wave * 16 + quad * 4 + r;
      if (row < M) {
        int col = n0 + nt * 16 + l16;
        float v = acc[nt][r];
        if (bias) v += bias[col];
        if (f32out) ((float*)C)[(size_t)row * N + col] = v;
        else ((unsigned short*)C)[(size_t)row * N + col] = f2bf(v);
      }
    }
  }
}

// ---------------------------------------------------------------------------
// Attention v2: 4 threads per q-row, each owning 16 of 64 head dims.
// Per-thread state: qf[16]+outv[16] (~55 VGPR, structurally no spill).
// QK dot completed via shfl_xor(1),(2) across the 4-lane group.
// Block 256 = 64 q-rows; K/V head slices staged in LDS.
// hs[b,s,h*64+d] = base + mask[s]*boost*ip     (hs stored bf16)
// ---------------------------------------------------------------------------
__global__ __launch_bounds__(256) void attn_k(
    const unsigned short* __restrict__ Q, const unsigned short* __restrict__ Kb,
    const unsigned short* __restrict__ Vb, const unsigned short* __restrict__ Kip,
    const unsigned short* __restrict__ Vip, const float* __restrict__ mask,
    const float* __restrict__ boostp, unsigned short* __restrict__ hs) {
  __shared__ unsigned short Ks[SKV_ * HD_];   // 9856 B
  __shared__ unsigned short Vs[SKV_ * HD_];   // 9856 B
  __shared__ float obase[256 * 17];           // 17 KB, stride 17 breaks conflicts

  const int tid = threadIdx.x;
  const int bh = blockIdx.y;
  const int b = bh / H_, h = bh % H_;
  const int qlocal = tid >> 2;                // 0..63
  const int dpart = tid & 3;                  // 0..3 -> d0 = dpart*16
  const int s = blockIdx.x * 64 + qlocal;
  const int d0 = dpart * 16;

  auto stage = [&](const unsigned short* K1, const unsigned short* V1) {
    for (int idx = tid; idx < SKV_ * 16; idx += 256) {
      int row = idx >> 4, c4 = idx & 15;
      size_t goff = (size_t)(b * SKV_ + row) * D_ + h * HD_ + c4 * 4;
      *(uint2*)(Ks + row * HD_ + c4 * 4) = *(const uint2*)(K1 + goff);
      *(uint2*)(Vs + row * HD_ + c4 * 4) = *(const uint2*)(V1 + goff);
    }
  };

  // this thread's 16 q components (fp32)
  float qf[16];
  {
    const uint4* qp = (const uint4*)(Q + (size_t)(b * S_ + s) * D_ + h * HD_ + d0);
#pragma unroll
    for (int i = 0; i < 2; ++i) {
      uint4 v = qp[i];
      qf[i * 8 + 0] = cvtlo(v.x); qf[i * 8 + 1] = cvthi(v.x);
      qf[i * 8 + 2] = cvtlo(v.y); qf[i * 8 + 3] = cvthi(v.y);
      qf[i * 8 + 4] = cvtlo(v.z); qf[i * 8 + 5] = cvthi(v.z);
      qf[i * 8 + 6] = cvtlo(v.w); qf[i * 8 + 7] = cvthi(v.w);
    }
  }

  float outv[16];
  auto branch = [&]() {
#pragma unroll
    for (int d = 0; d < 16; ++d) outv[d] = 0.f;
    float mrun = -1e30f, lrun = 0.f;
    for (int j = 0; j < SKV_; ++j) {
      float sum = 0.f;
      const uint4* kr = (const uint4*)(Ks + j * HD_ + d0);
#pragma unroll
      for (int i = 0; i < 2; ++i) {
        uint4 v = kr[i];
        sum = fmaf(qf[i * 8 + 0], cvtlo(v.x), sum); sum = fmaf(qf[i * 8 + 1], cvthi(v.x), sum);
        sum = fmaf(qf[i * 8 + 2], cvtlo(v.y), sum); sum = fmaf(qf[i * 8 + 3], cvthi(v.y), sum);
        sum = fmaf(qf[i * 8 + 4], cvtlo(v.z), sum); sum = fmaf(qf[i * 8 + 5], cvthi(v.z), sum);
        sum = fmaf(qf[i * 8 + 6], cvtlo(v.w), sum); sum = fmaf(qf[i * 8 + 7], cvthi(v.w), sum);
      }
      // complete the 64-dim dot across the 4-lane group
      sum += __shfl_xor(sum, 1, 64);
      sum += __shfl_xor(sum, 2, 64);
      float sc = sum * 0.125f;  // 1/sqrt(64)
      float mn = fmaxf(mrun, sc);
      float alpha = __expf(mrun - mn);
      float p = __expf(sc - mn);
      lrun = lrun * alpha + p;
      if (alpha != 1.0f) {
#pragma unroll
        for (int d = 0; d < 16; ++d) outv[d] *= alpha;
      }
      const uint4* vr = (const uint4*)(Vs + j * HD_ + d0);
#pragma unroll
      for (int i = 0; i < 2; ++i) {
        uint4 v = vr[i];
        outv[i * 8 + 0] = fmaf(p, cvtlo(v.x), outv[i * 8 + 0]);
        outv[i * 8 + 1] = fmaf(p, cvthi(v.x), outv[i * 8 + 1]);
        outv[i * 8 + 2] = fmaf(p, cvtlo(v.y), outv[i * 8 + 2]);
        outv[i * 8 + 3] = fmaf(p, cvthi(v.y), outv[i * 8 + 3]);
        outv[i * 8 + 4] = fmaf(p, cvtlo(v.z), outv[i * 8 + 4]);
        outv[i * 8 + 5] = fmaf(p, cvthi(v.z), outv[i * 8 + 5]);
        outv[i * 8 + 6] = fmaf(p, cvtlo(v.w), outv[i * 8 + 6]);
        outv[i * 8 + 7] = fmaf(p, cvthi(v.w), outv[i * 8 + 7]);
      }
      mrun = mn;
    }
    float inv = 1.0f / lrun;
#pragma unroll
    for (int d = 0; d < 16; ++d) outv[d] *= inv;
  };

  // base branch -> stash fp32 in LDS
  stage(Kb, Vb);
  __syncthreads();
  branch();
#pragma unroll
  for (int d = 0; d < 16; ++d) obase[tid * 17 + d] = outv[d];
  __syncthreads();  // all reads of Ks/Vs done before re-stage

  // ip branch
  stage(Kip, Vip);
  __syncthreads();
  branch();

  const float scale = mask[s] * boostp[0];
  unsigned short* op = hs + (size_t)(b * S_ + s) * D_ + h * HD_ + d0;
#pragma unroll
  for (int i = 0; i < 2; ++i) {
    unsigned int w[4];
#pragma unroll
    for (int k2 = 0; k2 < 4; ++k2) {
      int d = i * 8 + k2 * 2;
      unsigned short lo = f2bf(obase[tid * 17 + d] + scale * outv[d]);
      unsigned short hi = f2bf(obase[tid * 17 + d + 1] + scale * outv[d + 1]);
      w[k2] = (unsigned int)lo | ((unsigned int)hi << 16);
    }
    uint4 v; v.x = w[0]; v.y = w[1]; v.z = w[2]; v.w = w[3];
    ((uint4*)op)[i] = v;
  }
}

// ---------------------------------------------------------------------------
extern "C" void kernel_launch(void* const* d_in, const int* in_sizes, int n_in,
                              void* d_out, int out_size, void* d_ws, size_t ws_size,
                              hipStream_t stream) {
  const float* hidden = (const float*)d_in[0];
  const float* enc    = (const float*)d_in[1];
  const float* mask   = (const float*)d_in[2];
  const float* Wq     = (const float*)d_in[3];
  const float* Wk     = (const float*)d_in[4];
  const float* Wv     = (const float*)d_in[5];
  const float* Wkip   = (const float*)d_in[6];
  const float* Wvip   = (const float*)d_in[7];
  const float* Wo     = (const float*)d_in[8];
  const float* bo     = (const float*)d_in[9];

  char* ws = (char*)d_ws;
  unsigned short* cHid  = (unsigned short*)(ws + 0ULL);           // 41,943,040
  unsigned short* hsb   = cHid;                                   // alias (cHid dead after Q-proj)
  unsigned short* cEnc  = (unsigned short*)(ws + 41943040ULL);
  unsigned short* cWq   = (unsigned short*)(ws + 43204608ULL);
  unsigned short* cWk   = (unsigned short*)(ws + 46481408ULL);
  unsigned short* cWv   = (unsigned short*)(ws + 51724288ULL);
  unsigned short* cWkip = (unsigned short*)(ws + 56967168ULL);
  unsigned short* cWvip = (unsigned short*)(ws + 62210048ULL);
  unsigned short* cWo   = (unsigned short*)(ws + 67452928ULL);
  unsigned short* Qb    = (unsigned short*)(ws + 70729728ULL);
  unsigned short* Kb    = (unsigned short*)(ws + 112672768ULL);
  unsigned short* Vb    = (unsigned short*)(ws + 113461248ULL);
  unsigned short* Kip   = (unsigned short*)(ws + 114249728ULL);
  unsigned short* Vip   = (unsigned short*)(ws + 115038208ULL);
  float* boostp         = (float*)(ws + 115826688ULL);

  struct CvtJob { const float* src; unsigned short* dst; int n; };
  const CvtJob jobs[8] = {
      {hidden, cHid, B_ * S_ * D_},  {enc, cEnc, B_ * SKV_ * CD_},
      {Wq, cWq, D_ * D_},            {Wk, cWk, CD_ * D_},
      {Wv, cWv, CD_ * D_},           {Wkip, cWkip, CD_ * D_},
      {Wvip, cWvip, CD_ * D_},       {Wo, cWo, D_ * D_}};
  for (int i = 0; i < 8; ++i) {
    int n4 = jobs[i].n >> 2;
    int g = (n4 + 255) / 256; if (g > 4096) g = 4096;
    convert_k<<<dim3(g), dim3(256), 0, stream>>>(jobs[i].src, jobs[i].dst, n4);
  }

  boost_k<<<dim3(1), dim3(256), 0, stream>>>(mask, boostp);

  const int MQ = B_ * S_;    // 16384
  const int MKV = B_ * SKV_; // 308

  gemm_bf16<<<dim3(256, 20), dim3(256), 0, stream>>>(cHid, cWq, Qb, MQ, D_, D_,
                                                     nullptr, 0);
  gemm_bf16<<<dim3(5, 20), dim3(256), 0, stream>>>(cEnc, cWk, Kb, MKV, D_, CD_, nullptr, 0);
  gemm_bf16<<<dim3(5, 20), dim3(256), 0, stream>>>(cEnc, cWv, Vb, MKV, D_, CD_, nullptr, 0);
  gemm_bf16<<<dim3(5, 20), dim3(256), 0, stream>>>(cEnc, cWkip, Kip, MKV, D_, CD_, nullptr, 0);
  gemm_bf16<<<dim3(5, 20), dim3(256), 0, stream>>>(cEnc, cWvip, Vip, MKV, D_, CD_, nullptr, 0);

  // fused two-branch attention: 64 q-rows/block, 4 threads per q-row
  attn_k<<<dim3(S_ / 64, B_ * H_), dim3(256), 0, stream>>>(Qb, Kb, Vb, Kip, Vip,
                                                           mask, boostp, hsb);

  // out = hsb @ Wo + bo   (fp32 output + fp32 bias)
  gemm_bf16<<<dim3(256, 20), dim3(256), 0, stream>>>(hsb, cWo, d_out, MQ, D_, D_,
                                                     bo, 1);
}

// Round 5
// 879.323 us; speedup vs baseline: 8.6400x; 1.4973x over previous
//
#include <hip/hip_runtime.h>
#include <stdint.h>

// Problem constants
#define B_   4
#define S_   4096
#define D_   1280
#define H_   20
#define HD_  64
#define SKV_ 77
#define CD_  2048

typedef short bfrag8 __attribute__((ext_vector_type(8)));   // 8 bf16 = 4 VGPRs
typedef float f32x4  __attribute__((ext_vector_type(4)));

__device__ __forceinline__ float bf2f(unsigned short h) {
  return __uint_as_float(((unsigned int)h) << 16);
}
__device__ __forceinline__ unsigned short f2bf(float f) {
  unsigned int u = __float_as_uint(f);
  unsigned int r = (u + 0x7FFFu + ((u >> 16) & 1u)) >> 16;  // RNE
  return (unsigned short)r;
}
__device__ __forceinline__ float cvtlo(unsigned int u) { return __uint_as_float(u << 16); }
__device__ __forceinline__ float cvthi(unsigned int u) { return __uint_as_float(u & 0xFFFF0000u); }

// async global->LDS, 16B per lane. LDS dest = wave-uniform base + lane*16,
// which our chunk mapping (c = i*256 + tid, lds off = c*16) satisfies.
__device__ __forceinline__ void async16(const unsigned short* g, unsigned short* l) {
  __builtin_amdgcn_global_load_lds(
      (const __attribute__((address_space(1))) unsigned int*)g,
      (__attribute__((address_space(3))) unsigned int*)l, 16, 0, 0);
}

// ---------------------------------------------------------------------------
// fp32 -> bf16 conversion (vectorized)
// ---------------------------------------------------------------------------
__global__ __launch_bounds__(256) void convert_k(const float* __restrict__ src,
                                                 unsigned short* __restrict__ dst,
                                                 int n4) {
  for (int i = blockIdx.x * 256 + threadIdx.x; i < n4; i += gridDim.x * 256) {
    float4 v = ((const float4*)src)[i];
    uint2 o;
    o.x = (unsigned int)f2bf(v.x) | ((unsigned int)f2bf(v.y) << 16);
    o.y = (unsigned int)f2bf(v.z) | ((unsigned int)f2bf(v.w) << 16);
    ((uint2*)dst)[i] = o;
  }
}

// ---------------------------------------------------------------------------
// fp32 [K,N] -> bf16 transposed [N,K], 32x32 LDS tile (both sides coalesced)
// ---------------------------------------------------------------------------
__global__ __launch_bounds__(256) void convtr_k(const float* __restrict__ src,
                                                unsigned short* __restrict__ dst,
                                                int K, int N) {
  __shared__ float t[32][33];
  const int k0 = blockIdx.x * 32, n0 = blockIdx.y * 32;
  const int r = threadIdx.x >> 3, c4 = threadIdx.x & 7;
  float4 v = *(const float4*)(src + (size_t)(k0 + r) * N + n0 + c4 * 4);
  t[r][c4 * 4 + 0] = v.x; t[r][c4 * 4 + 1] = v.y;
  t[r][c4 * 4 + 2] = v.z; t[r][c4 * 4 + 3] = v.w;
  __syncthreads();
  uint2 o;
  o.x = (unsigned int)f2bf(t[c4 * 4 + 0][r]) | ((unsigned int)f2bf(t[c4 * 4 + 1][r]) << 16);
  o.y = (unsigned int)f2bf(t[c4 * 4 + 2][r]) | ((unsigned int)f2bf(t[c4 * 4 + 3][r]) << 16);
  *(uint2*)(dst + (size_t)(n0 + r) * K + k0 + c4 * 4) = o;
}

// ---------------------------------------------------------------------------
// boost scalar
// ---------------------------------------------------------------------------
__global__ __launch_bounds__(256) void boost_k(const float* __restrict__ mask,
                                               float* __restrict__ outp) {
  __shared__ float red[4];
  float s = 0.f;
  for (int i = threadIdx.x; i < S_; i += 256) s += mask[i];
#pragma unroll
  for (int off = 32; off > 0; off >>= 1) s += __shfl_down(s, off, 64);
  int wave = threadIdx.x >> 6, lane = threadIdx.x & 63;
  if (lane == 0) red[wave] = s;
  __syncthreads();
  if (threadIdx.x == 0) {
    float t = red[0] + red[1] + red[2] + red[3];
    float ratio = t * (1.0f / (float)S_);
    float boost = (ratio > 1e-6f && ratio < 0.1f)
                      ? fminf(1.0f + (0.1f - ratio) * 30.0f, 4.0f)
                      : 1.0f;
    outp[0] = boost;
  }
}

// ---------------------------------------------------------------------------
// m97-style GEMM: C[M,N] = A[M,K] @ Bt[N,K]^T (+bias). 128x128 tile, BK=32,
// global_load_lds width-16 staging, 4 waves each computing 64x64 (4x4 MFMA).
// Requires M%128==0, N%128==0, K%32==0 (true for all call sites).
// ---------------------------------------------------------------------------
__global__ __launch_bounds__(256) void gemm_bt128(
    const unsigned short* __restrict__ A, const unsigned short* __restrict__ Bt,
    void* __restrict__ C, int M, int N, int K,
    const float* __restrict__ bias, int f32out) {
  __shared__ unsigned short As[128 * 32];  // 8 KB, unpadded (global_load_lds order)
  __shared__ unsigned short Bs[128 * 32];  // 8 KB, rows = n

  const int tid = threadIdx.x;
  const int m0 = blockIdx.x * 128, n0 = blockIdx.y * 128;
  const int wave = tid >> 6, lane = tid & 63;
  const int wm = (wave >> 1) * 64, wn = (wave & 1) * 64;
  const int l16 = lane & 15, quad = lane >> 4;

  f32x4 acc[4][4] = {};

  for (int k0 = 0; k0 < K; k0 += 32) {
#pragma unroll
    for (int i = 0; i < 2; ++i) {
      int c = i * 256 + tid;
      int r = c >> 2, kc = c & 3;
      async16(A + (size_t)(m0 + r) * K + k0 + kc * 8, As + c * 8);
      async16(Bt + (size_t)(n0 + r) * K + k0 + kc * 8, Bs + c * 8);
    }
    __syncthreads();

    bfrag8 af[4], bf[4];
#pragma unroll
    for (int t = 0; t < 4; ++t) {
      af[t] = *(const bfrag8*)(As + (wm + t * 16 + l16) * 32 + quad * 8);
      bf[t] = *(const bfrag8*)(Bs + (wn + t * 16 + l16) * 32 + quad * 8);
    }
#pragma unroll
    for (int mt = 0; mt < 4; ++mt)
#pragma unroll
      for (int nt = 0; nt < 4; ++nt)
        acc[mt][nt] =
            __builtin_amdgcn_mfma_f32_16x16x32_bf16(af[mt], bf[nt], acc[mt][nt], 0, 0, 0);
    __syncthreads();
  }

  // D layout: row = quad*4 + r, col = lane&15
#pragma unroll
  for (int mt = 0; mt < 4; ++mt) {
#pragma unroll
    for (int nt = 0; nt < 4; ++nt) {
#pragma unroll
      for (int r = 0; r < 4; ++r) {
        int row = m0 + wm + mt * 16 + quad * 4 + r;
        int col = n0 + wn + nt * 16 + l16;
        float v = acc[mt][nt][r];
        if (bias) v += bias[col];
        if (f32out) ((float*)C)[(size_t)row * N + col] = v;
        else ((unsigned short*)C)[(size_t)row * N + col] = f2bf(v);
      }
    }
  }
}

// ---------------------------------------------------------------------------
// small GEMM for KV projections (M=308): 64x64 tile, bounds-checked M.
// ---------------------------------------------------------------------------
__global__ __launch_bounds__(256) void gemm_bf16(
    const unsigned short* __restrict__ A, const unsigned short* __restrict__ Bw,
    unsigned short* __restrict__ C, int M, int N, int K) {
  __shared__ unsigned short As[64][40];
  __shared__ unsigned short Bs[64][40];

  const int tid = threadIdx.x;
  const int m0 = blockIdx.x * 64, n0 = blockIdx.y * 64;
  const int wave = tid >> 6, lane = tid & 63;
  const int l16 = lane & 15, quad = lane >> 4;

  f32x4 acc[4] = {};

  for (int k0 = 0; k0 < K; k0 += 32) {
    {
      int row = tid >> 2, kc = tid & 3;
      int gr = m0 + row;
      uint4 v = make_uint4(0u, 0u, 0u, 0u);
      if (gr < M) v = *(const uint4*)(A + (size_t)gr * K + k0 + kc * 8);
      *(uint4*)&As[row][kc * 8] = v;
    }
    {
      int kk = tid >> 3, n8 = tid & 7;
      uint4 v = *(const uint4*)(Bw + (size_t)(k0 + kk) * N + n0 + n8 * 8);
      unsigned short* p = (unsigned short*)&v;
#pragma unroll
      for (int j = 0; j < 8; ++j) Bs[n8 * 8 + j][kk] = p[j];
    }
    __syncthreads();

    bfrag8 af = *(const bfrag8*)&As[wave * 16 + l16][quad * 8];
#pragma unroll
    for (int nt = 0; nt < 4; ++nt) {
      bfrag8 bf = *(const bfrag8*)&Bs[nt * 16 + l16][quad * 8];
      acc[nt] = __builtin_amdgcn_mfma_f32_16x16x32_bf16(af, bf, acc[nt], 0, 0, 0);
    }
    __syncthreads();
  }

#pragma unroll
  for (int nt = 0; nt < 4; ++nt) {
#pragma unroll
    for (int r = 0; r < 4; ++r) {
      int row = m0 + wave * 16 + quad * 4 + r;
      if (row < M) {
        int col = n0 + nt * 16 + l16;
        C[(size_t)row * N + col] = f2bf(acc[nt][r]);
      }
    }
  }
}

// ---------------------------------------------------------------------------
// Attention v3: 4 threads per q-row (16 dims each). K/V staged in LDS as
// *fp32* (kills the per-j bf16 unpack ops). Base-branch output kept in regs.
// hs[b,s,h*64+d] = base + mask[s]*boost*ip   (hs stored bf16)
// ---------------------------------------------------------------------------
__global__ __launch_bounds__(256) void attn_k(
    const unsigned short* __restrict__ Q, const unsigned short* __restrict__ Kb,
    const unsigned short* __restrict__ Vb, const unsigned short* __restrict__ Kip,
    const unsigned short* __restrict__ Vip, const float* __restrict__ mask,
    const float* __restrict__ boostp, unsigned short* __restrict__ hs) {
  __shared__ float Ks[SKV_ * HD_];   // 19712 B
  __shared__ float Vs[SKV_ * HD_];   // 19712 B

  const int tid = threadIdx.x;
  const int bh = blockIdx.y;
  const int b = bh / H_, h = bh % H_;
  const int qlocal = tid >> 2;
  const int dpart = tid & 3;
  const int s = blockIdx.x * 64 + qlocal;
  const int d0 = dpart * 16;

  auto stage = [&](const unsigned short* K1, const unsigned short* V1) {
    for (int idx = tid; idx < SKV_ * 16; idx += 256) {
      int row = idx >> 4, c4 = idx & 15;
      size_t goff = (size_t)(b * SKV_ + row) * D_ + h * HD_ + c4 * 4;
      uint2 kv = *(const uint2*)(K1 + goff);
      uint2 vv = *(const uint2*)(V1 + goff);
      float4 kf4 = make_float4(cvtlo(kv.x), cvthi(kv.x), cvtlo(kv.y), cvthi(kv.y));
      float4 vf4 = make_float4(cvtlo(vv.x), cvthi(vv.x), cvtlo(vv.y), cvthi(vv.y));
      *(float4*)(Ks + row * HD_ + c4 * 4) = kf4;
      *(float4*)(Vs + row * HD_ + c4 * 4) = vf4;
    }
  };

  float qf[16];
  {
    const uint4* qp = (const uint4*)(Q + (size_t)(b * S_ + s) * D_ + h * HD_ + d0);
#pragma unroll
    for (int i = 0; i < 2; ++i) {
      uint4 v = qp[i];
      qf[i * 8 + 0] = cvtlo(v.x); qf[i * 8 + 1] = cvthi(v.x);
      qf[i * 8 + 2] = cvtlo(v.y); qf[i * 8 + 3] = cvthi(v.y);
      qf[i * 8 + 4] = cvtlo(v.z); qf[i * 8 + 5] = cvthi(v.z);
      qf[i * 8 + 6] = cvtlo(v.w); qf[i * 8 + 7] = cvthi(v.w);
    }
  }

  float outv[16];
  auto branch = [&]() {
#pragma unroll
    for (int d = 0; d < 16; ++d) outv[d] = 0.f;
    float mrun = -1e30f, lrun = 0.f;
    for (int j = 0; j < SKV_; ++j) {
      const float4* kr = (const float4*)(Ks + j * HD_ + d0);
      float sum = 0.f;
#pragma unroll
      for (int i = 0; i < 4; ++i) {
        float4 v = kr[i];
        sum = fmaf(qf[i * 4 + 0], v.x, sum);
        sum = fmaf(qf[i * 4 + 1], v.y, sum);
        sum = fmaf(qf[i * 4 + 2], v.z, sum);
        sum = fmaf(qf[i * 4 + 3], v.w, sum);
      }
      sum += __shfl_xor(sum, 1, 64);
      sum += __shfl_xor(sum, 2, 64);
      float sc = sum * 0.125f;  // 1/sqrt(64)
      float mn = fmaxf(mrun, sc);
      float alpha = __expf(mrun - mn);
      float p = __expf(sc - mn);
      lrun = lrun * alpha + p;
      const float4* vr = (const float4*)(Vs + j * HD_ + d0);
#pragma unroll
      for (int i = 0; i < 4; ++i) {
        float4 v = vr[i];
        outv[i * 4 + 0] = fmaf(outv[i * 4 + 0], alpha, p * v.x);
        outv[i * 4 + 1] = fmaf(outv[i * 4 + 1], alpha, p * v.y);
        outv[i * 4 + 2] = fmaf(outv[i * 4 + 2], alpha, p * v.z);
        outv[i * 4 + 3] = fmaf(outv[i * 4 + 3], alpha, p * v.w);
      }
      mrun = mn;
    }
    float inv = 1.0f / lrun;
#pragma unroll
    for (int d = 0; d < 16; ++d) outv[d] *= inv;
  };

  // base branch -> keep in registers
  stage(Kb, Vb);
  __syncthreads();
  branch();
  float obase[16];
#pragma unroll
  for (int d = 0; d < 16; ++d) obase[d] = outv[d];
  __syncthreads();  // all Ks/Vs reads done before re-stage

  // ip branch
  stage(Kip, Vip);
  __syncthreads();
  branch();

  const float scale = mask[s] * boostp[0];
  unsigned short* op = hs + (size_t)(b * S_ + s) * D_ + h * HD_ + d0;
#pragma unroll
  for (int i = 0; i < 2; ++i) {
    unsigned int w[4];
#pragma unroll
    for (int k2 = 0; k2 < 4; ++k2) {
      int d = i * 8 + k2 * 2;
      unsigned short lo = f2bf(obase[d] + scale * outv[d]);
      unsigned short hi = f2bf(obase[d + 1] + scale * outv[d + 1]);
      w[k2] = (unsigned int)lo | ((unsigned int)hi << 16);
    }
    uint4 v; v.x = w[0]; v.y = w[1]; v.z = w[2]; v.w = w[3];
    ((uint4*)op)[i] = v;
  }
}

// ---------------------------------------------------------------------------
extern "C" void kernel_launch(void* const* d_in, const int* in_sizes, int n_in,
                              void* d_out, int out_size, void* d_ws, size_t ws_size,
                              hipStream_t stream) {
  const float* hidden = (const float*)d_in[0];
  const float* enc    = (const float*)d_in[1];
  const float* mask   = (const float*)d_in[2];
  const float* Wq     = (const float*)d_in[3];
  const float* Wk     = (const float*)d_in[4];
  const float* Wv     = (const float*)d_in[5];
  const float* Wkip   = (const float*)d_in[6];
  const float* Wvip   = (const float*)d_in[7];
  const float* Wo     = (const float*)d_in[8];
  const float* bo     = (const float*)d_in[9];

  char* ws = (char*)d_ws;
  unsigned short* cHid  = (unsigned short*)(ws + 0ULL);           // 41,943,040
  unsigned short* hsb   = cHid;                                   // alias (cHid dead after Q-proj)
  unsigned short* cEnc  = (unsigned short*)(ws + 41943040ULL);
  unsigned short* cWqT  = (unsigned short*)(ws + 43204608ULL);    // [N,K] transposed
  unsigned short* cWk   = (unsigned short*)(ws + 46481408ULL);
  unsigned short* cWv   = (unsigned short*)(ws + 51724288ULL);
  unsigned short* cWkip = (unsigned short*)(ws + 56967168ULL);
  unsigned short* cWvip = (unsigned short*)(ws + 62210048ULL);
  unsigned short* cWoT  = (unsigned short*)(ws + 67452928ULL);    // [N,K] transposed
  unsigned short* Qb    = (unsigned short*)(ws + 70729728ULL);
  unsigned short* Kb    = (unsigned short*)(ws + 112672768ULL);
  unsigned short* Vb    = (unsigned short*)(ws + 113461248ULL);
  unsigned short* Kip   = (unsigned short*)(ws + 114249728ULL);
  unsigned short* Vip   = (unsigned short*)(ws + 115038208ULL);
  float* boostp         = (float*)(ws + 115826688ULL);

  struct CvtJob { const float* src; unsigned short* dst; int n; };
  const CvtJob jobs[6] = {
      {hidden, cHid, B_ * S_ * D_},  {enc, cEnc, B_ * SKV_ * CD_},
      {Wk, cWk, CD_ * D_},           {Wv, cWv, CD_ * D_},
      {Wkip, cWkip, CD_ * D_},       {Wvip, cWvip, CD_ * D_}};
  for (int i = 0; i < 6; ++i) {
    int n4 = jobs[i].n >> 2;
    int g = (n4 + 255) / 256; if (g > 4096) g = 4096;
    convert_k<<<dim3(g), dim3(256), 0, stream>>>(jobs[i].src, jobs[i].dst, n4);
  }
  // transposed weights for the two big GEMMs (B^T operand for m97 structure)
  convtr_k<<<dim3(D_ / 32, D_ / 32), dim3(256), 0, stream>>>(Wq, cWqT, D_, D_);
  convtr_k<<<dim3(D_ / 32, D_ / 32), dim3(256), 0, stream>>>(Wo, cWoT, D_, D_);

  boost_k<<<dim3(1), dim3(256), 0, stream>>>(mask, boostp);

  const int MQ = B_ * S_;    // 16384
  const int MKV = B_ * SKV_; // 308

  // Q = hidden @ Wq  (128-tile async GEMM; 16384/1280/1280 all tile-exact)
  gemm_bt128<<<dim3(MQ / 128, D_ / 128), dim3(256), 0, stream>>>(
      cHid, cWqT, Qb, MQ, D_, D_, nullptr, 0);

  gemm_bf16<<<dim3(5, 20), dim3(256), 0, stream>>>(cEnc, cWk, Kb, MKV, D_, CD_);
  gemm_bf16<<<dim3(5, 20), dim3(256), 0, stream>>>(cEnc, cWv, Vb, MKV, D_, CD_);
  gemm_bf16<<<dim3(5, 20), dim3(256), 0, stream>>>(cEnc, cWkip, Kip, MKV, D_, CD_);
  gemm_bf16<<<dim3(5, 20), dim3(256), 0, stream>>>(cEnc, cWvip, Vip, MKV, D_, CD_);

  attn_k<<<dim3(S_ / 64, B_ * H_), dim3(256), 0, stream>>>(Qb, Kb, Vb, Kip, Vip,
                                                           mask, boostp, hsb);

  // out = hsb @ Wo + bo  (fp32 output)
  gemm_bt128<<<dim3(MQ / 128, D_ / 128), dim3(256), 0, stream>>>(
      hsb, cWoT, d_out, MQ, D_, D_, bo, 1);
}